// Round 2
// baseline (590.073 us; speedup 1.0000x reference)
//
#include <hip/hip_runtime.h>

#define NN 8192
#define CIN 256
#define COUT 128
#define JT 32
#define WLCAP 4096
#define AGG_T 1024

__device__ __forceinline__ float lrelu_exp(float t) {
    return __expf(t >= 0.0f ? t : 0.2f * t);
}

// ---------------- Kernel A: h = x @ W (fp32) + fused a_src/a_dst ----------
// 32 rows/block, 256 threads, 4x4 thread tile. x tile staged in LDS
// [row][k] padded to 257 (breaks the 32-way row-broadcast bank conflict);
// W streamed from global (128 KB, L1/L2-hot). Epilogue reduces
// h[i]·att_src and h[i]·att_dst across the 32-thread column groups.
__global__ __launch_bounds__(256) void gemm_h(const float* __restrict__ x,
                                              const float* __restrict__ W,
                                              const float* __restrict__ att_src,
                                              const float* __restrict__ att_dst,
                                              float* __restrict__ h,
                                              float* __restrict__ a_src,
                                              float* __restrict__ a_dst) {
    __shared__ float xs[32][CIN + 1];   // 32.9 KB
    int tid = threadIdx.x;
    int i0 = blockIdx.x * 32;
    {
        int r = tid >> 3;              // 0..31
        int kq = (tid & 7) * 32;       // 8 chunks of 32 k's
        const float* xrow = x + (size_t)(i0 + r) * CIN + kq;
        #pragma unroll
        for (int q = 0; q < 8; ++q) {
            float4 v = *(const float4*)(xrow + q * 4);
            xs[r][kq + q * 4 + 0] = v.x;
            xs[r][kq + q * 4 + 1] = v.y;
            xs[r][kq + q * 4 + 2] = v.z;
            xs[r][kq + q * 4 + 3] = v.w;
        }
    }
    __syncthreads();
    int tx = tid & 31, ty = tid >> 5;
    int c0 = tx * 4, r0 = ty * 4;
    float acc[4][4] = {};
    #pragma unroll 4
    for (int k = 0; k < CIN; ++k) {
        float4 wv = *(const float4*)&W[k * COUT + c0];
        float xf[4];
        #pragma unroll
        for (int a = 0; a < 4; ++a) xf[a] = xs[r0 + a][k];
        #pragma unroll
        for (int a = 0; a < 4; ++a) {
            acc[a][0] += xf[a] * wv.x;
            acc[a][1] += xf[a] * wv.y;
            acc[a][2] += xf[a] * wv.z;
            acc[a][3] += xf[a] * wv.w;
        }
    }
    float4 asv = *(const float4*)&att_src[c0];
    float4 adv = *(const float4*)&att_dst[c0];
    #pragma unroll
    for (int a = 0; a < 4; ++a) {
        float4 o = make_float4(acc[a][0], acc[a][1], acc[a][2], acc[a][3]);
        *(float4*)&h[(size_t)(i0 + r0 + a) * COUT + c0] = o;
        float s = o.x * asv.x + o.y * asv.y + o.z * asv.z + o.w * asv.w;
        float d = o.x * adv.x + o.y * adv.y + o.z * adv.z + o.w * adv.w;
        #pragma unroll
        for (int m = 16; m >= 1; m >>= 1) {
            s += __shfl_xor(s, m, 32);
            d += __shfl_xor(d, m, 32);
        }
        if (tx == 0) {
            a_src[i0 + r0 + a] = s;
            a_dst[i0 + r0 + a] = d;
        }
    }
}

// ---------------- Kernel B: scan adj stripe, compact nonzeros, aggregate ----
// Block owns 32 output columns (j0..j0+31): a 128 B-wide, 128 B-aligned
// stripe -> every fetched cache line belongs entirely to this block (no
// over-fetch). Phase 1: uint4 scan (4 cols/lane, 128 rows/iter, register
// double-buffered) compacting nonzeros into an LDS worklist; denominators
// via LDS float atomics. Diagonal excluded in-scan; forced self-loop added
// exactly once. Phase 2: one wave per entry, acc[jl][c] += w*h[i][c].
__global__ __launch_bounds__(AGG_T) void gat_agg(const float* __restrict__ adj,
                                                 const float* __restrict__ h,
                                                 const float* __restrict__ a_src,
                                                 const float* __restrict__ a_dst,
                                                 const float* __restrict__ bias,
                                                 float* __restrict__ out) {
    __shared__ float accS[JT * COUT];       // 16 KB
    __shared__ float denomS[JT];
    __shared__ float adstS[JT];
    __shared__ unsigned int wlMeta[WLCAP];  // 16 KB
    __shared__ float wlW[WLCAP];            // 16 KB
    __shared__ int wlcnt;

    int tid = threadIdx.x;
    int j0 = blockIdx.x * JT;

    for (int t = tid; t < JT * COUT; t += AGG_T) accS[t] = 0.0f;
    if (tid < JT) { denomS[tid] = 0.0f; adstS[tid] = a_dst[j0 + tid]; }
    if (tid == 0) wlcnt = 0;
    __syncthreads();

    // forced self-loops: added exactly once (real diagonal excluded below)
    if (tid < JT) {
        int i = j0 + tid;
        float w = lrelu_exp(a_src[i] + adstS[tid]);
        int pos = atomicAdd(&wlcnt, 1);
        wlMeta[pos] = ((unsigned)i << 5) | (unsigned)tid;
        wlW[pos] = w;
        atomicAdd(&denomS[tid], w);
    }

    // scan: lane covers 4 adjacent columns (uint4), 128 rows/iter
    int jg = tid & 7;         // column quad 0..7
    int isub = tid >> 3;      // 0..127
    int jbase = jg * 4;
    const float* colbase = adj + j0 + jbase;
    uint4 v = *(const uint4*)(colbase + (size_t)isub * NN);
    for (int ib = 0; ib < NN; ib += 128) {
        int i = ib + isub;
        uint4 vn = make_uint4(0u, 0u, 0u, 0u);
        if (ib + 128 < NN)
            vn = *(const uint4*)(colbase + (size_t)(i + 128) * NN);
        if (v.x | v.y | v.z | v.w) {
            float si = a_src[i];
            unsigned int vv[4] = {v.x, v.y, v.z, v.w};
            #pragma unroll
            for (int q = 0; q < 4; ++q) {
                if (vv[q] != 0u) {
                    int jl = jbase + q;
                    if (i != j0 + jl) {   // true diagonal handled above
                        float val = __uint_as_float(vv[q]);
                        float w = val * lrelu_exp(si + adstS[jl]);
                        int pos = atomicAdd(&wlcnt, 1);
                        if (pos < WLCAP) {
                            wlMeta[pos] = ((unsigned)i << 5) | (unsigned)jl;
                            wlW[pos] = w;
                        }
                        atomicAdd(&denomS[jl], w);
                    }
                }
            }
        }
        v = vn;
    }
    __syncthreads();

    // phase 2: one wave per worklist entry
    int cnt = wlcnt < WLCAP ? wlcnt : WLCAP;
    int wave = tid >> 6, lane = tid & 63;
    for (int e = wave; e < cnt; e += AGG_T / 64) {
        unsigned int m = wlMeta[e];
        float w = wlW[e];
        int i = (int)(m >> 5);
        int jl = (int)(m & 31u);
        float2 hv = *(const float2*)&h[(size_t)i * COUT + lane * 2];
        atomicAdd(&accS[jl * COUT + lane * 2],     w * hv.x);
        atomicAdd(&accS[jl * COUT + lane * 2 + 1], w * hv.y);
    }
    __syncthreads();

    // epilogue: normalize + bias, one float4 per thread
    int jl = tid >> 5;
    int c = (tid & 31) * 4;
    float inv = 1.0f / denomS[jl];
    float4 a = *(const float4*)&accS[jl * COUT + c];
    float4 b = *(const float4*)&bias[c];
    float4 o = make_float4(a.x * inv + b.x, a.y * inv + b.y,
                           a.z * inv + b.z, a.w * inv + b.w);
    *(float4*)&out[(size_t)(j0 + jl) * COUT + c] = o;
}

extern "C" void kernel_launch(void* const* d_in, const int* in_sizes, int n_in,
                              void* d_out, int out_size, void* d_ws, size_t ws_size,
                              hipStream_t stream) {
    const float* x       = (const float*)d_in[0];
    const float* adj     = (const float*)d_in[1];
    const float* W       = (const float*)d_in[2];
    const float* att_src = (const float*)d_in[3];
    const float* att_dst = (const float*)d_in[4];
    const float* bias    = (const float*)d_in[5];
    float* out = (float*)d_out;

    float* h     = (float*)d_ws;                 // 8192*128*4 = 4 MB
    float* a_src = h + (size_t)NN * COUT;        // 32 KB
    float* a_dst = a_src + NN;                   // 32 KB

    gemm_h <<<NN / 32, 256, 0, stream>>>(x, W, att_src, att_dst, h, a_src, a_dst);
    gat_agg<<<NN / JT, AGG_T, 0, stream>>>(adj, h, a_src, a_dst, bias, out);
}